// Round 5
// baseline (126.768 us; speedup 1.0000x reference)
//
#include <hip/hip_runtime.h>

#define F        128
#define NN       768
#define KE       192          // effective RBF range: d<=17.33 -> centers >=19.2 are dead
#define E_STRIDE 56           // elems; per-row 48-slot window (octet-aligned) + 8 slack
                              // 112 B/row = 7*16 -> b128-aligned rows, 7 coprime 8 spreads banks
#define H_STRIDE 136          // elems; 272 B stride == 16 mod 128 (proven conflict-free layout)
#define NT       48           // number of 16-row tiles
#define NBLK     (NT*(NT+1)/2)   // 1176 upper-triangular tile pairs

#define L2E 1.44269504f
#define LN2 0.69314718f
#define DQS 3782.0f           // d quantizer: d<=17.33 -> d*3782 <= 65507 fits u16
#define DQI (1.0f/3782.0f)

typedef __attribute__((ext_vector_type(8))) short short8;
typedef __attribute__((ext_vector_type(4))) float floatx4;

__device__ __forceinline__ unsigned short f2bf(float f) {
    union { float f; unsigned u; } v; v.f = f;
    return (unsigned short)((v.u + 0x8000u) >> 16);   // round-half-up (2 VALU)
}

// pack two f32 -> two bf16 (RTNE) in ONE VALU op
__device__ __forceinline__ unsigned cvt_pk_bf16(float lo, float hi) {
    unsigned r;
    asm("v_cvt_pk_bf16_f32 %0, %1, %2" : "=v"(r) : "v"(lo), "v"(hi));
    return r;
}

// z already in log2 domain (z = preact*log2e; bias*log2e folded into MFMA acc-init,
// log2e folded into packed W). ssp = ln2*(log2(1 + 2^z) - 1); bounded inputs.
__device__ __forceinline__ float ssp_l2(float zl2e) {
    float t = exp2f(zl2e);                  // v_exp_f32
    float u = __log2f(1.0f + t);            // v_add + v_log_f32
    return fmaf(LN2, u, -LN2);
}

// opaque pin: compiler can no longer rematerialize/sink the loaded value
__device__ __forceinline__ void pin(short8& v) { asm volatile("" : "+v"(v)); }

// LDS-only barrier: drain DS ops, do NOT drain vmcnt -> out-atomics stay in flight
// (no cross-wave communication through global memory inside this kernel)
__device__ __forceinline__ void bar_lds() {
    asm volatile("s_waitcnt lgkmcnt(0)" ::: "memory");
    __builtin_amdgcn_s_barrier();
}

__device__ __forceinline__ int klo_from_d(float d) {
    int k = (int)ceilf(fmaf(10.0f, d, -13.0f));  // |d - 0.1k| > 1.3 -> e < 5e-8
    k &= ~1;
    return k < 0 ? 0 : (k > KE - 32 ? KE - 32 : k);
}

// Pack W1[0:192][128] and W2[128][128] (f32, PRE-SCALED by log2e) into bf16 MFMA
// B-fragment order, and zero the output buffer (replaces a separate memset node).
// elem idx = ((ks*8 + nt)*64 + lane)*8 + t ; k = ks*32 + (lane>>4)*8 + t ; n = nt*16 + (lane&15)
__global__ void prep_w(const float* __restrict__ W1, const float* __restrict__ W2,
                       unsigned short* __restrict__ W1s, unsigned short* __restrict__ W2s,
                       float* __restrict__ out) {
    int idx = blockIdx.x * 256 + threadIdx.x;          // grid covers 98304 = NN*F
    out[idx] = 0.0f;
    if (idx < KE * F) {                                // 24576
        int t = idx & 7, lane = (idx >> 3) & 63, frag = idx >> 9;   // frag 0..47
        int k = (frag >> 3) * 32 + (lane >> 4) * 8 + t;             // < 192
        int n = (frag & 7) * 16 + (lane & 15);
        W1s[idx] = f2bf(W1[k * F + n] * L2E);
    } else if (idx < KE * F + F * F) {                 // next 16384
        int j = idx - KE * F;
        int t = j & 7, lane = (j >> 3) & 63, frag = j >> 9;         // frag 0..31
        int k = (frag >> 3) * 32 + (lane >> 4) * 8 + t;             // < 128
        int n = (frag & 7) * 16 + (lane & 15);
        W2s[j] = f2bf(W2[k * F + n] * L2E);
    }
}

// (256,2): allocator free, no spills. DO NOT tighten: (256,3)/(256,4) caused
// scratch spills (70+ MB HBM spill traffic, +19% dur — round 2/3 post-mortems).
__global__ __launch_bounds__(256, 2) void cfconv_main(
    const float* __restrict__ x, const float* __restrict__ r,
    const float* __restrict__ b1, const float* __restrict__ b2,
    const unsigned short* __restrict__ W1s, const unsigned short* __restrict__ W2s,
    float* __restrict__ out)
{
    // Two sub-tiles (u=0,1) live per loop iteration: 2 barriers cover 2 sub-tiles
    // (was 2 barriers per 1). epi(u0) overlaps GEMM(u1) in the barrier-free region.
    __shared__ __align__(16) unsigned short e_lds[2][64 * E_STRIDE];  // 14336 B
    __shared__ __align__(16) unsigned short h_lds[2][64 * H_STRIDE];  // 34816 B
    __shared__ unsigned short d_all[256];                             // u16 fixed-point d
    __shared__ unsigned short klo8_lds[2][64];                        // per-row window base
    // total LDS = 49920 B -> 3 blocks/CU (LDS-wise)

    const int tid  = threadIdx.x;
    const int lane = tid & 63;
    const int wave = tid >> 6;
    const int quad = lane >> 4;
    const int l15  = lane & 15;

    // ---- decode upper-triangular tile pair (A <= B); f(A) = A*(97-A)/2 ----
    int b = blockIdx.x;
    int A = (int)((97.0f - sqrtf(9409.0f - 8.0f * (float)b)) * 0.5f);
    while ((A + 1) * (97 - (A + 1)) / 2 <= b) ++A;
    while (A * (97 - A) / 2 > b) --A;
    const int B = A + (b - A * (97 - A) / 2);
    const int Ai0 = A * 16, Bj0 = B * 16;
    const bool diag = (A == B);

    // ---- hoist ALL B-fragments into VGPRs (invariant across the s-iters) and PIN them ----
    short8 w1f[6][2], w2f[4][2];
    #pragma unroll
    for (int ks = 0; ks < KE / 32; ++ks) {
        w1f[ks][0] = *(const short8*)&W1s[((ks*8 + wave*2 + 0) * 64 + lane) * 8];
        w1f[ks][1] = *(const short8*)&W1s[((ks*8 + wave*2 + 1) * 64 + lane) * 8];
    }
    #pragma unroll
    for (int ks = 0; ks < F / 32; ++ks) {
        w2f[ks][0] = *(const short8*)&W2s[((ks*8 + wave*2 + 0) * 64 + lane) * 8];
        w2f[ks][1] = *(const short8*)&W2s[((ks*8 + wave*2 + 1) * 64 + lane) * 8];
    }
    #pragma unroll
    for (int ks = 0; ks < 6; ++ks) { pin(w1f[ks][0]); pin(w1f[ks][1]); }
    #pragma unroll
    for (int ks = 0; ks < 4; ++ks) { pin(w2f[ks][0]); pin(w2f[ks][1]); }

    // ---- distances for all 256 (ii,jj) pairs (u16 fixed point; proven path) ----
    {
        int p = tid;
        int gi = Ai0 + (p >> 4), gj = Bj0 + (p & 15);
        float dx = r[gi*3+0] - r[gj*3+0];
        float dy = r[gi*3+1] - r[gj*3+1];
        float dz = r[gi*3+2] - r[gj*3+2];
        float sq = dx*dx + dy*dy + dz*dz;
        float d  = sq > 0.0f ? sqrtf(sq) : 0.0f;
        d_all[p] = (unsigned short)fmaf(d, DQS, 0.5f);
    }

    const int c0 = wave * 32 + l15;                // this wave's column strip
    const int c1 = c0 + 16;
    const float b1L0 = b1[c0] * L2E, b1L1 = b1[c1] * L2E;   // bias pre-scaled to log2 domain
    const float b2L0 = b2[c0] * L2E, b2L1 = b2[c1] * L2E;

    // x rows of the B tile, indexed by this thread's quad: jj = quad*4 + rg
    float xB0[4], xB1[4];
    #pragma unroll
    for (int rg = 0; rg < 4; ++rg) {
        int gj = Bj0 + quad * 4 + rg;
        xB0[rg] = x[gj * F + c0];
        xB1[rg] = x[gj * F + c1];
    }
    float oB0[4] = {0,0,0,0}, oB1[4] = {0,0,0,0};

    const int rq16 = 16 * ((l15 >> 2) & 3);        // h-swizzle offset for A-frag reads

    bar_lds();                                     // d_all visible to all waves

    for (int sp = 0; sp < 2; ++sp) {
        // ---- fill BOTH sub-tile windows: 4 threads per row, full 48-slot rewrite ----
        {
            int row = tid >> 2;                    // 0..63
            int lo4 = tid & 3;
            #pragma unroll
            for (int u = 0; u < 2; ++u) {
                float d = (float)d_all[(sp*2 + u) * 64 + row] * DQI;
                int klo8 = klo_from_d(d) & ~7;     // octet-aligned window base
                if (lo4 == 0) klo8_lds[u][row] = (unsigned short)klo8;
                #pragma unroll
                for (int pass = 0; pass < 12; ++pass) {
                    int loc = lo4 + pass * 4;      // 0..47
                    float t = fmaf(-0.1f, (float)(klo8 + loc), d);
                    float e = exp2f(t * t * (-10.0f * L2E));
                    e_lds[u][row * E_STRIDE + loc] = f2bf(e);
                }
            }
        }
        bar_lds();

        // ---- GEMM1 + epilogue1 for u=0 then u=1 (no barrier between: epi1(u0)'s
        //      VALU/TRANS overlaps GEMM1(u1)'s MFMA+LDS) ----
        #pragma unroll
        for (int u = 0; u < 2; ++u) {
            floatx4 acc[4][2];
            {
                floatx4 bi0 = {b1L0, b1L0, b1L0, b1L0};
                floatx4 bi1 = {b1L1, b1L1, b1L1, b1L1};
                #pragma unroll
                for (int mt = 0; mt < 4; ++mt) { acc[mt][0] = bi0; acc[mt][1] = bi1; }
            }
            int klo8r[4];
            #pragma unroll
            for (int mt = 0; mt < 4; ++mt) klo8r[mt] = klo8_lds[u][mt*16 + l15];
            __builtin_amdgcn_s_setprio(1);
            #pragma unroll
            for (int ks = 0; ks < KE / 32; ++ks) {
                short8 af[4];
                #pragma unroll
                for (int mt = 0; mt < 4; ++mt) {
                    int off = ks*32 + quad*8 - klo8r[mt];          // multiple of 8
                    off = ((unsigned)off > 32u) ? 40 : off;        // 40.. = zero pad
                    af[mt] = *(const short8*)&e_lds[u][(mt*16 + l15) * E_STRIDE + off];
                }
                #pragma unroll
                for (int mt = 0; mt < 4; ++mt) {
                    acc[mt][0] = __builtin_amdgcn_mfma_f32_16x16x32_bf16(af[mt], w1f[ks][0], acc[mt][0], 0, 0, 0);
                    acc[mt][1] = __builtin_amdgcn_mfma_f32_16x16x32_bf16(af[mt], w1f[ks][1], acc[mt][1], 0, 0, 0);
                }
            }
            __builtin_amdgcn_s_setprio(0);

            // epilogue 1: h = ssp(acc) -> swizzled LDS (proven rq16 rotation)
            #pragma unroll
            for (int mt = 0; mt < 4; ++mt) {
                #pragma unroll
                for (int rg = 0; rg < 4; ++rg) {
                    int row = mt*16 + quad*4 + rg;     // (row>>2)&3 == quad
                    float h0 = ssp_l2(acc[mt][0][rg]);
                    float h1 = ssp_l2(acc[mt][1][rg]);
                    unsigned pk = cvt_pk_bf16(h0, h1); // 1 VALU for both conversions
                    h_lds[u][row * H_STRIDE + ((c0 + 16*quad) & 127)] = (unsigned short)pk;
                    h_lds[u][row * H_STRIDE + ((c1 + 16*quad) & 127)] = (unsigned short)(pk >> 16);
                }
            }
        }
        bar_lds();

        // ---- GEMM2 + epilogue2 for u=0 then u=1 (epi2(u0) overlaps GEMM2(u1)) ----
        #pragma unroll
        for (int u = 0; u < 2; ++u) {
            const int s = sp*2 + u;

            // xA prefetch: issue before GEMM2 so L2 latency hides under 32 MFMAs
            float xA0[4], xA1[4];
            #pragma unroll
            for (int mt = 0; mt < 4; ++mt) {
                int gi = Ai0 + s*4 + mt;
                xA0[mt] = x[gi * F + c0];
                xA1[mt] = x[gi * F + c1];
            }

            floatx4 acc2[4][2];
            {
                floatx4 bi0 = {b2L0, b2L0, b2L0, b2L0};
                floatx4 bi1 = {b2L1, b2L1, b2L1, b2L1};
                #pragma unroll
                for (int mt = 0; mt < 4; ++mt) { acc2[mt][0] = bi0; acc2[mt][1] = bi1; }
            }
            __builtin_amdgcn_s_setprio(1);
            #pragma unroll
            for (int ks = 0; ks < F / 32; ++ks) {
                int ko = (ks*32 + quad*8 + rq16) & 127;
                short8 af[4];
                #pragma unroll
                for (int mt = 0; mt < 4; ++mt)
                    af[mt] = *(const short8*)&h_lds[u][(mt*16 + l15) * H_STRIDE + ko];
                #pragma unroll
                for (int mt = 0; mt < 4; ++mt) {
                    acc2[mt][0] = __builtin_amdgcn_mfma_f32_16x16x32_bf16(af[mt], w2f[ks][0], acc2[mt][0], 0, 0, 0);
                    acc2[mt][1] = __builtin_amdgcn_mfma_f32_16x16x32_bf16(af[mt], w2f[ks][1], acc2[mt][1], 0, 0, 0);
                }
            }
            __builtin_amdgcn_s_setprio(0);

            // epilogue 2: w = ssp(acc2); o_A += xB*w ; o_B += xA*w
            float oA0[4] = {0,0,0,0}, oA1[4] = {0,0,0,0};
            #pragma unroll
            for (int mt = 0; mt < 4; ++mt) {
                #pragma unroll
                for (int rg = 0; rg < 4; ++rg) {
                    float w0 = ssp_l2(acc2[mt][0][rg]);
                    float w1 = ssp_l2(acc2[mt][1][rg]);
                    oA0[mt] = fmaf(xB0[rg], w0, oA0[mt]);
                    oA1[mt] = fmaf(xB1[rg], w1, oA1[mt]);
                    if (!diag) {
                        oB0[rg] = fmaf(xA0[mt], w0, oB0[rg]);
                        oB1[rg] = fmaf(xA1[mt], w1, oB1[rg]);
                    }
                }
            }
            // reduce o_A across quads (rows complete within this sub-tile) and scatter;
            // atomics are never vmcnt-drained in-loop (bar_lds waits lgkm only)
            #pragma unroll
            for (int mt = 0; mt < 4; ++mt) {
                oA0[mt] += __shfl_xor(oA0[mt], 16, 64); oA0[mt] += __shfl_xor(oA0[mt], 32, 64);
                oA1[mt] += __shfl_xor(oA1[mt], 16, 64); oA1[mt] += __shfl_xor(oA1[mt], 32, 64);
            }
            if (lane < 16) {
                #pragma unroll
                for (int mt = 0; mt < 4; ++mt) {
                    int gi = Ai0 + s*4 + mt;
                    atomicAdd(&out[gi * F + c0], oA0[mt]);
                    atomicAdd(&out[gi * F + c1], oA1[mt]);
                }
            }
        }
    }

    // ---- scatter o_B (complete over all ii; one owner-thread per (jj,col)) ----
    if (!diag) {
        #pragma unroll
        for (int rg = 0; rg < 4; ++rg) {
            int gj = Bj0 + quad * 4 + rg;
            atomicAdd(&out[gj * F + c0], oB0[rg]);
            atomicAdd(&out[gj * F + c1], oB1[rg]);
        }
    }
}

extern "C" void kernel_launch(void* const* d_in, const int* in_sizes, int n_in,
                              void* d_out, int out_size, void* d_ws, size_t ws_size,
                              hipStream_t stream) {
    const float* x  = (const float*)d_in[0];
    const float* r  = (const float*)d_in[1];
    const float* W1 = (const float*)d_in[2];
    const float* b1 = (const float*)d_in[3];
    const float* W2 = (const float*)d_in[4];
    const float* b2 = (const float*)d_in[5];
    float* out = (float*)d_out;

    unsigned short* W1s = (unsigned short*)d_ws;       // 24576 bf16 (pre-scaled by log2e)
    unsigned short* W2s = W1s + KE * F;                // 16384 bf16 (pre-scaled by log2e)

    prep_w<<<(NN * F) / 256, 256, 0, stream>>>(W1, W2, W1s, W2s, out);  // pack + zero out
    cfconv_main<<<NBLK, 256, 0, stream>>>(x, r, b1, b2, W1s, W2s, out);
}

// Round 6
// 122.050 us; speedup vs baseline: 1.0387x; 1.0387x over previous
//
#include <hip/hip_runtime.h>

#define F        128
#define NN       768
#define KE       192          // effective RBF range: d<=17.33 -> centers >=19.2 are dead
#define E_STRIDE 56           // elems; per-row 48-slot window (octet-aligned) + 8 slack
                              // 112 B/row = 7*16 -> b128-aligned rows, 7 coprime 8 spreads banks
#define H_STRIDE 136          // elems; 272 B stride == 16 mod 128 (proven conflict-free layout)
#define NT       48           // number of 16-row tiles
#define NBLK     (NT*(NT+1)/2)   // 1176 upper-triangular tile pairs

#define L2E 1.44269504f
#define LN2 0.69314718f
#define DQS 3782.0f           // d quantizer: d<=17.33 -> d*3782 <= 65507 fits u16
#define DQI (1.0f/3782.0f)

typedef __attribute__((ext_vector_type(8))) short short8;
typedef __attribute__((ext_vector_type(4))) float floatx4;

__device__ __forceinline__ unsigned short f2bf(float f) {
    union { float f; unsigned u; } v; v.f = f;
    return (unsigned short)((v.u + 0x8000u) >> 16);   // round-half-up (2 VALU)
}

// pack two f32 -> two bf16 (RTNE) in ONE VALU op
__device__ __forceinline__ unsigned cvt_pk_bf16(float lo, float hi) {
    unsigned r;
    asm("v_cvt_pk_bf16_f32 %0, %1, %2" : "=v"(r) : "v"(lo), "v"(hi));
    return r;
}

// z already in log2 domain (z = preact*log2e; bias*log2e folded into MFMA acc-init,
// log2e folded into packed W). ssp = ln2*(log2(1 + 2^z) - 1); bounded inputs.
__device__ __forceinline__ float ssp_l2(float zl2e) {
    float t = exp2f(zl2e);                  // v_exp_f32
    float u = __log2f(1.0f + t);            // v_add + v_log_f32
    return fmaf(LN2, u, -LN2);
}

// opaque pin: compiler can no longer rematerialize/sink the loaded value
__device__ __forceinline__ void pin(short8& v) { asm volatile("" : "+v"(v)); }

// LDS-only barrier: drain DS ops, do NOT drain vmcnt -> out-atomics stay in flight
// (no cross-wave communication through global memory inside this kernel)
__device__ __forceinline__ void bar_lds() {
    asm volatile("s_waitcnt lgkmcnt(0)" ::: "memory");
    __builtin_amdgcn_s_barrier();
}

__device__ __forceinline__ int klo_from_d(float d) {
    int k = (int)ceilf(fmaf(10.0f, d, -13.0f));  // |d - 0.1k| > 1.3 -> e < 5e-8
    k &= ~1;
    return k < 0 ? 0 : (k > KE - 32 ? KE - 32 : k);
}

// Pack W1[0:192][128] and W2[128][128] (f32, PRE-SCALED by log2e) into bf16 MFMA
// B-fragment order, and zero the output buffer (replaces a separate memset node).
// elem idx = ((ks*8 + nt)*64 + lane)*8 + t ; k = ks*32 + (lane>>4)*8 + t ; n = nt*16 + (lane&15)
__global__ void prep_w(const float* __restrict__ W1, const float* __restrict__ W2,
                       unsigned short* __restrict__ W1s, unsigned short* __restrict__ W2s,
                       float* __restrict__ out) {
    int idx = blockIdx.x * 256 + threadIdx.x;          // grid covers 98304 = NN*F
    out[idx] = 0.0f;
    if (idx < KE * F) {                                // 24576
        int t = idx & 7, lane = (idx >> 3) & 63, frag = idx >> 9;   // frag 0..47
        int k = (frag >> 3) * 32 + (lane >> 4) * 8 + t;             // < 192
        int n = (frag & 7) * 16 + (lane & 15);
        W1s[idx] = f2bf(W1[k * F + n] * L2E);
    } else if (idx < KE * F + F * F) {                 // next 16384
        int j = idx - KE * F;
        int t = j & 7, lane = (j >> 3) & 63, frag = j >> 9;         // frag 0..31
        int k = (frag >> 3) * 32 + (lane >> 4) * 8 + t;             // < 128
        int n = (frag & 7) * 16 + (lane & 15);
        W2s[j] = f2bf(W2[k * F + n] * L2E);
    }
}

// (256,2): allocator free, no spills. DO NOT tighten: (256,3)/(256,4) caused
// scratch spills (70+ MB HBM spill traffic, +19% dur — round 2/3 post-mortems).
__global__ __launch_bounds__(256, 2) void cfconv_main(
    const float* __restrict__ x, const float* __restrict__ r,
    const float* __restrict__ b1, const float* __restrict__ b2,
    const unsigned short* __restrict__ W1s, const unsigned short* __restrict__ W2s,
    float* __restrict__ out)
{
    // Windowed E-tile: row rr stores e(klo8[rr] + loc) for loc in [0,48); the true
    // 32-wide window [klo, klo+31] is always inside [klo8, klo8+38]; slots 40..47
    // compute to exact 0 (|d-0.1k| >= 2.5) and double as the clamp-read zero pad.
    __shared__ __align__(16) unsigned short e_lds[64 * E_STRIDE];   // 7168 B
    __shared__ __align__(16) unsigned short h_lds[64 * H_STRIDE];   // 17408 B
    __shared__ unsigned short d_all[256];                           // u16 fixed-point d
    __shared__ unsigned short klo8_lds[64];                         // per-row window base
    // total LDS = 25216 B (block size 25600)

    const int tid  = threadIdx.x;
    const int lane = tid & 63;
    const int wave = tid >> 6;
    const int quad = lane >> 4;
    const int l15  = lane & 15;

    // ---- decode upper-triangular tile pair (A <= B); f(A) = A*(97-A)/2 ----
    int b = blockIdx.x;
    int A = (int)((97.0f - sqrtf(9409.0f - 8.0f * (float)b)) * 0.5f);
    while ((A + 1) * (97 - (A + 1)) / 2 <= b) ++A;
    while (A * (97 - A) / 2 > b) --A;
    const int B = A + (b - A * (97 - A) / 2);
    const int Ai0 = A * 16, Bj0 = B * 16;
    const bool diag = (A == B);
    // stagger the sub-tile order per block: same-A blocks hit different out rows
    // at any instant -> less line contention on the device-scope atomics
    const int s0 = (A + 3 * B) & 3;

    // ---- hoist ALL B-fragments into VGPRs (invariant across the 4 s-iters) and PIN them ----
    short8 w1f[6][2], w2f[4][2];
    #pragma unroll
    for (int ks = 0; ks < KE / 32; ++ks) {
        w1f[ks][0] = *(const short8*)&W1s[((ks*8 + wave*2 + 0) * 64 + lane) * 8];
        w1f[ks][1] = *(const short8*)&W1s[((ks*8 + wave*2 + 1) * 64 + lane) * 8];
    }
    #pragma unroll
    for (int ks = 0; ks < F / 32; ++ks) {
        w2f[ks][0] = *(const short8*)&W2s[((ks*8 + wave*2 + 0) * 64 + lane) * 8];
        w2f[ks][1] = *(const short8*)&W2s[((ks*8 + wave*2 + 1) * 64 + lane) * 8];
    }
    #pragma unroll
    for (int ks = 0; ks < 6; ++ks) { pin(w1f[ks][0]); pin(w1f[ks][1]); }
    #pragma unroll
    for (int ks = 0; ks < 4; ++ks) { pin(w2f[ks][0]); pin(w2f[ks][1]); }

    // ---- distances for all 256 (ii,jj) pairs (u16 fixed point; proven path) ----
    {
        int p = tid;
        int gi = Ai0 + (p >> 4), gj = Bj0 + (p & 15);
        float dx = r[gi*3+0] - r[gj*3+0];
        float dy = r[gi*3+1] - r[gj*3+1];
        float dz = r[gi*3+2] - r[gj*3+2];
        float sq = dx*dx + dy*dy + dz*dz;
        float d  = sq > 0.0f ? sqrtf(sq) : 0.0f;
        d_all[p] = (unsigned short)fmaf(d, DQS, 0.5f);
    }

    const int c0 = wave * 32 + l15;                // this wave's column strip
    const int c1 = c0 + 16;
    const float b1L0 = b1[c0] * L2E, b1L1 = b1[c1] * L2E;   // bias pre-scaled to log2 domain
    const float b2L0 = b2[c0] * L2E, b2L1 = b2[c1] * L2E;

    // x rows of the B tile, indexed by this thread's quad: jj = quad*4 + rg
    float xB0[4], xB1[4];
    #pragma unroll
    for (int rg = 0; rg < 4; ++rg) {
        int gj = Bj0 + quad * 4 + rg;
        xB0[rg] = x[gj * F + c0];
        xB1[rg] = x[gj * F + c1];
    }
    float oB0[4] = {0,0,0,0}, oB1[4] = {0,0,0,0};

    const int rq16 = 16 * ((l15 >> 2) & 3);        // h-swizzle offset for A-frag reads

    // deferred oA scatter state (issued one iteration late, AFTER the next
    // iteration's xA loads, so xA consumption waits vmcnt(16) instead of
    // draining fresh contended atomics — vmcnt retires in order)
    float oA0_sv[4], oA1_sv[4];
    int giA_sv = 0;

    bar_lds();                                     // d_all visible to all waves

    for (int si = 0; si < 4; ++si) {
        const int s = (si + s0) & 3;

        // ---- xA loads FIRST (oldest in the vmem queue this iteration) ----
        float xA0[4], xA1[4];
        #pragma unroll
        for (int mt = 0; mt < 4; ++mt) {
            int gi = Ai0 + s*4 + mt;
            xA0[mt] = x[gi * F + c0];
            xA1[mt] = x[gi * F + c1];
        }
        // ---- now issue the PREVIOUS sub-tile's oA atomics: they sit behind xA
        //      in the queue, so epi2's xA wait is vmcnt(16) and drains at most
        //      the atomics from two iterations ago (~2 full iters of cover) ----
        if (si > 0 && lane < 16) {
            #pragma unroll
            for (int mt = 0; mt < 4; ++mt) {
                atomicAdd(&out[(giA_sv + mt) * F + c0], oA0_sv[mt]);
                atomicAdd(&out[(giA_sv + mt) * F + c1], oA1_sv[mt]);
            }
        }

        // ---- fill: 4 threads per row write the full 48-slot window (no clears,
        //      no init: every readable slot is rewritten each s-iter) ----
        {
            int row = tid >> 2;                    // 0..63
            int lo4 = tid & 3;
            float d = (float)d_all[s * 64 + row] * DQI;
            int klo8 = klo_from_d(d) & ~7;         // octet-aligned window base
            if (lo4 == 0) klo8_lds[row] = (unsigned short)klo8;
            #pragma unroll
            for (int pass = 0; pass < 12; ++pass) {
                int loc = lo4 + pass * 4;          // 0..47
                float t = fmaf(-0.1f, (float)(klo8 + loc), d);
                float e = exp2f(t * t * (-10.0f * L2E));
                e_lds[row * E_STRIDE + loc] = f2bf(e);
            }
        }
        bar_lds();

        // ---- GEMM1: windowed E @ W1(regs); A-frags read per-lane at off = k - klo8[row],
        //      clamped to the zero pad when the octet misses the row's window ----
        floatx4 acc[4][2];
        {
            floatx4 bi0 = {b1L0, b1L0, b1L0, b1L0};
            floatx4 bi1 = {b1L1, b1L1, b1L1, b1L1};
            #pragma unroll
            for (int mt = 0; mt < 4; ++mt) { acc[mt][0] = bi0; acc[mt][1] = bi1; }
        }
        int klo8r[4];
        #pragma unroll
        for (int mt = 0; mt < 4; ++mt) klo8r[mt] = klo8_lds[mt*16 + l15];
        __builtin_amdgcn_s_setprio(1);
        #pragma unroll
        for (int ks = 0; ks < KE / 32; ++ks) {
            short8 af[4];
            #pragma unroll
            for (int mt = 0; mt < 4; ++mt) {
                int off = ks*32 + quad*8 - klo8r[mt];          // multiple of 8
                off = ((unsigned)off > 32u) ? 40 : off;        // 40.. = zero pad
                af[mt] = *(const short8*)&e_lds[(mt*16 + l15) * E_STRIDE + off];
            }
            #pragma unroll
            for (int mt = 0; mt < 4; ++mt) {
                acc[mt][0] = __builtin_amdgcn_mfma_f32_16x16x32_bf16(af[mt], w1f[ks][0], acc[mt][0], 0, 0, 0);
                acc[mt][1] = __builtin_amdgcn_mfma_f32_16x16x32_bf16(af[mt], w1f[ks][1], acc[mt][1], 0, 0, 0);
            }
        }
        __builtin_amdgcn_s_setprio(0);

        // ---- epilogue 1: h = ssp(acc) -> swizzled LDS (proven rq16 rotation) ----
        #pragma unroll
        for (int mt = 0; mt < 4; ++mt) {
            #pragma unroll
            for (int rg = 0; rg < 4; ++rg) {
                int row = mt*16 + quad*4 + rg;     // (row>>2)&3 == quad
                float h0 = ssp_l2(acc[mt][0][rg]);
                float h1 = ssp_l2(acc[mt][1][rg]);
                unsigned pk = cvt_pk_bf16(h0, h1); // 1 VALU for both conversions
                h_lds[row * H_STRIDE + ((c0 + 16*quad) & 127)] = (unsigned short)pk;
                h_lds[row * H_STRIDE + ((c1 + 16*quad) & 127)] = (unsigned short)(pk >> 16);
            }
        }
        bar_lds();

        // ---- GEMM2: h[64 x 128] @ W2(regs, pre-scaled); acc2 init = bias*log2e ----
        floatx4 acc2[4][2];
        {
            floatx4 bi0 = {b2L0, b2L0, b2L0, b2L0};
            floatx4 bi1 = {b2L1, b2L1, b2L1, b2L1};
            #pragma unroll
            for (int mt = 0; mt < 4; ++mt) { acc2[mt][0] = bi0; acc2[mt][1] = bi1; }
        }
        __builtin_amdgcn_s_setprio(1);
        #pragma unroll
        for (int ks = 0; ks < F / 32; ++ks) {
            int ko = (ks*32 + quad*8 + rq16) & 127;
            short8 af[4];
            #pragma unroll
            for (int mt = 0; mt < 4; ++mt)
                af[mt] = *(const short8*)&h_lds[(mt*16 + l15) * H_STRIDE + ko];
            #pragma unroll
            for (int mt = 0; mt < 4; ++mt) {
                acc2[mt][0] = __builtin_amdgcn_mfma_f32_16x16x32_bf16(af[mt], w2f[ks][0], acc2[mt][0], 0, 0, 0);
                acc2[mt][1] = __builtin_amdgcn_mfma_f32_16x16x32_bf16(af[mt], w2f[ks][1], acc2[mt][1], 0, 0, 0);
            }
        }
        __builtin_amdgcn_s_setprio(0);

        // ---- epilogue 2: w = ssp(acc2); o_A += xB*w ; o_B += xA*w ----
        float oA0[4] = {0,0,0,0}, oA1[4] = {0,0,0,0};
        #pragma unroll
        for (int mt = 0; mt < 4; ++mt) {
            #pragma unroll
            for (int rg = 0; rg < 4; ++rg) {
                float w0 = ssp_l2(acc2[mt][0][rg]);
                float w1 = ssp_l2(acc2[mt][1][rg]);
                oA0[mt] = fmaf(xB0[rg], w0, oA0[mt]);
                oA1[mt] = fmaf(xB1[rg], w1, oA1[mt]);
                if (!diag) {
                    oB0[rg] = fmaf(xA0[mt], w0, oB0[rg]);
                    oB1[rg] = fmaf(xA1[mt], w1, oB1[rg]);
                }
            }
        }
        // reduce o_A across quads (rows complete within this sub-tile); defer the
        // scatter to the top of the next iteration (atomics never block the pipe)
        #pragma unroll
        for (int mt = 0; mt < 4; ++mt) {
            oA0[mt] += __shfl_xor(oA0[mt], 16, 64); oA0[mt] += __shfl_xor(oA0[mt], 32, 64);
            oA1[mt] += __shfl_xor(oA1[mt], 16, 64); oA1[mt] += __shfl_xor(oA1[mt], 32, 64);
            oA0_sv[mt] = oA0[mt]; oA1_sv[mt] = oA1[mt];
        }
        giA_sv = Ai0 + s*4;
    }

    // ---- drain the last sub-tile's oA (no loads follow -> fire and forget) ----
    if (lane < 16) {
        #pragma unroll
        for (int mt = 0; mt < 4; ++mt) {
            atomicAdd(&out[(giA_sv + mt) * F + c0], oA0_sv[mt]);
            atomicAdd(&out[(giA_sv + mt) * F + c1], oA1_sv[mt]);
        }
    }

    // ---- scatter o_B (complete over all ii; one owner-thread per (jj,col)) ----
    if (!diag) {
        #pragma unroll
        for (int rg = 0; rg < 4; ++rg) {
            int gj = Bj0 + quad * 4 + rg;
            atomicAdd(&out[gj * F + c0], oB0[rg]);
            atomicAdd(&out[gj * F + c1], oB1[rg]);
        }
    }
}

extern "C" void kernel_launch(void* const* d_in, const int* in_sizes, int n_in,
                              void* d_out, int out_size, void* d_ws, size_t ws_size,
                              hipStream_t stream) {
    const float* x  = (const float*)d_in[0];
    const float* r  = (const float*)d_in[1];
    const float* W1 = (const float*)d_in[2];
    const float* b1 = (const float*)d_in[3];
    const float* W2 = (const float*)d_in[4];
    const float* b2 = (const float*)d_in[5];
    float* out = (float*)d_out;

    unsigned short* W1s = (unsigned short*)d_ws;       // 24576 bf16 (pre-scaled by log2e)
    unsigned short* W2s = W1s + KE * F;                // 16384 bf16 (pre-scaled by log2e)

    prep_w<<<(NN * F) / 256, 256, 0, stream>>>(W1, W2, W1s, W2s, out);  // pack + zero out
    cfconv_main<<<NBLK, 256, 0, stream>>>(x, r, b1, b2, W1s, W2s, out);
}

// Round 7
// 119.337 us; speedup vs baseline: 1.0623x; 1.0227x over previous
//
#include <hip/hip_runtime.h>

#define F        128
#define NN       768
#define KE       192          // effective RBF range: d<=17.33 -> centers >=19.2 are dead
#define E_STRIDE 56           // elems; per-row 48-slot window (octet-aligned) + 8 slack
                              // 112 B/row = 7*16 -> b128-aligned rows, 7 coprime 8 spreads banks
#define H_STRIDE 136          // elems; 272 B stride == 16 mod 128 (proven conflict-free layout)
#define NT       48           // number of 16-row tiles
#define NPAIR    (NT*(NT+1)/2)   // 1176 upper-triangular tile pairs
#define NBLK     (NPAIR*4)       // 4704 blocks: one 64-pair slice each (s in blockIdx)

#define L2E 1.44269504f
#define LN2 0.69314718f

typedef __attribute__((ext_vector_type(8))) short short8;
typedef __attribute__((ext_vector_type(4))) float floatx4;

__device__ __forceinline__ unsigned short f2bf(float f) {
    union { float f; unsigned u; } v; v.f = f;
    return (unsigned short)((v.u + 0x8000u) >> 16);   // round-half-up (2 VALU)
}

// pack two f32 -> two bf16 (RTNE) in ONE VALU op
__device__ __forceinline__ unsigned cvt_pk_bf16(float lo, float hi) {
    unsigned r;
    asm("v_cvt_pk_bf16_f32 %0, %1, %2" : "=v"(r) : "v"(lo), "v"(hi));
    return r;
}

// z already in log2 domain (z = preact*log2e; bias*log2e folded into MFMA acc-init,
// log2e folded into packed W). ssp = ln2*(log2(1 + 2^z) - 1); bounded inputs.
__device__ __forceinline__ float ssp_l2(float zl2e) {
    float t = exp2f(zl2e);                  // v_exp_f32
    float u = __log2f(1.0f + t);            // v_add + v_log_f32
    return fmaf(LN2, u, -LN2);
}

// opaque pin: compiler can no longer rematerialize/sink the loaded value
__device__ __forceinline__ void pin(short8& v) { asm volatile("" : "+v"(v)); }

// LDS-only barrier: drain DS ops, do NOT drain vmcnt -> out-atomics stay in flight
// (no cross-wave communication through global memory inside this kernel)
__device__ __forceinline__ void bar_lds() {
    asm volatile("s_waitcnt lgkmcnt(0)" ::: "memory");
    __builtin_amdgcn_s_barrier();
}

__device__ __forceinline__ int klo_from_d(float d) {
    int k = (int)ceilf(fmaf(10.0f, d, -13.0f));  // |d - 0.1k| > 1.3 -> e < 5e-8
    k &= ~1;
    return k < 0 ? 0 : (k > KE - 32 ? KE - 32 : k);
}

// Pack W1[0:192][128] and W2[128][128] (f32, PRE-SCALED by log2e) into bf16 MFMA
// B-fragment order, and zero the output buffer (replaces a separate memset node).
// elem idx = ((ks*8 + nt)*64 + lane)*8 + t ; k = ks*32 + (lane>>4)*8 + t ; n = nt*16 + (lane&15)
__global__ void prep_w(const float* __restrict__ W1, const float* __restrict__ W2,
                       unsigned short* __restrict__ W1s, unsigned short* __restrict__ W2s,
                       float* __restrict__ out) {
    int idx = blockIdx.x * 256 + threadIdx.x;          // grid covers 98304 = NN*F
    out[idx] = 0.0f;
    if (idx < KE * F) {                                // 24576
        int t = idx & 7, lane = (idx >> 3) & 63, frag = idx >> 9;   // frag 0..47
        int k = (frag >> 3) * 32 + (lane >> 4) * 8 + t;             // < 192
        int n = (frag & 7) * 16 + (lane & 15);
        W1s[idx] = f2bf(W1[k * F + n] * L2E);
    } else if (idx < KE * F + F * F) {                 // next 16384
        int j = idx - KE * F;
        int t = j & 7, lane = (j >> 3) & 63, frag = j >> 9;         // frag 0..31
        int k = (frag >> 3) * 32 + (lane >> 4) * 8 + t;             // < 128
        int n = (frag & 7) * 16 + (lane & 15);
        W2s[j] = f2bf(W2[k * F + n] * L2E);
    }
}

// One block = one 64-pair slice (4 A-rows x 16 B-cols) of one tile pair.
// Grid 4704 = 18.4 blocks/CU: tail imbalance ~5% (was 25-30% at 1176 blocks with
// 2-3 resident), and co-resident blocks de-phase instead of convoying.
// (256,2): allocator free, no spills. DO NOT tighten: (256,3)/(256,4) caused
// scratch spills (70+ MB HBM spill traffic, +19% dur — round 2/3 post-mortems).
__global__ __launch_bounds__(256, 2) void cfconv_main(
    const float* __restrict__ x, const float* __restrict__ r,
    const float* __restrict__ b1, const float* __restrict__ b2,
    const unsigned short* __restrict__ W1s, const unsigned short* __restrict__ W2s,
    float* __restrict__ out)
{
    // Windowed E-tile: row rr stores e(klo8[rr] + loc) for loc in [0,48); the true
    // 32-wide window [klo, klo+31] is always inside [klo8, klo8+38]; slots 40..47
    // compute to exact 0 (|d-0.1k| >= 2.5) and double as the clamp-read zero pad.
    __shared__ __align__(16) unsigned short e_lds[64 * E_STRIDE];   // 7168 B
    __shared__ __align__(16) unsigned short h_lds[64 * H_STRIDE];   // 17408 B
    __shared__ float d_all[64];                                     // exact f32 d per pair
    __shared__ unsigned short klo8_lds[64];                         // per-row window base
    // total LDS = 24960 B

    const int tid  = threadIdx.x;
    const int lane = tid & 63;
    const int wave = tid >> 6;
    const int quad = lane >> 4;
    const int l15  = lane & 15;

    // ---- decode (tile pair, s-slice); f(A) = A*(97-A)/2 ----
    int bidx = blockIdx.x;
    const int s = bidx & 3;
    int b = bidx >> 2;                         // 0..1175 upper-triangular pair id
    int A = (int)((97.0f - sqrtf(9409.0f - 8.0f * (float)b)) * 0.5f);
    while ((A + 1) * (97 - (A + 1)) / 2 <= b) ++A;
    while (A * (97 - A) / 2 > b) --A;
    const int B = A + (b - A * (97 - A) / 2);
    const int Ai0 = A * 16, Bj0 = B * 16;
    const bool diag = (A == B);

    // ---- hoist ALL B-fragments into VGPRs and PIN them (W1s/W2s are 80 KB -> L2-hot) ----
    short8 w1f[6][2], w2f[4][2];
    #pragma unroll
    for (int ks = 0; ks < KE / 32; ++ks) {
        w1f[ks][0] = *(const short8*)&W1s[((ks*8 + wave*2 + 0) * 64 + lane) * 8];
        w1f[ks][1] = *(const short8*)&W1s[((ks*8 + wave*2 + 1) * 64 + lane) * 8];
    }
    #pragma unroll
    for (int ks = 0; ks < F / 32; ++ks) {
        w2f[ks][0] = *(const short8*)&W2s[((ks*8 + wave*2 + 0) * 64 + lane) * 8];
        w2f[ks][1] = *(const short8*)&W2s[((ks*8 + wave*2 + 1) * 64 + lane) * 8];
    }
    #pragma unroll
    for (int ks = 0; ks < 6; ++ks) { pin(w1f[ks][0]); pin(w1f[ks][1]); }
    #pragma unroll
    for (int ks = 0; ks < 4; ++ks) { pin(w2f[ks][0]); pin(w2f[ks][1]); }

    // ---- distances for this slice's 64 (ii,jj) pairs; rr = i_loc*16 + j_loc ----
    if (tid < 64) {
        int gi = Ai0 + s * 4 + (tid >> 4), gj = Bj0 + (tid & 15);
        float dx = r[gi*3+0] - r[gj*3+0];
        float dy = r[gi*3+1] - r[gj*3+1];
        float dz = r[gi*3+2] - r[gj*3+2];
        float sq = dx*dx + dy*dy + dz*dz;
        d_all[tid] = sq > 0.0f ? sqrtf(sq) : 0.0f;
    }

    const int c0 = wave * 32 + l15;                // this wave's column strip
    const int c1 = c0 + 16;
    const float b1L0 = b1[c0] * L2E, b1L1 = b1[c1] * L2E;   // bias pre-scaled to log2 domain
    const float b2L0 = b2[c0] * L2E, b2L1 = b2[c1] * L2E;

    // ---- xA loads FIRST (oldest in the vmem queue); all out-atomics issue last ----
    float xA0[4], xA1[4];
    #pragma unroll
    for (int mt = 0; mt < 4; ++mt) {
        int gi = Ai0 + s*4 + mt;
        xA0[mt] = x[gi * F + c0];
        xA1[mt] = x[gi * F + c1];
    }
    // x rows of the B tile, indexed by this thread's quad: jj = quad*4 + rg
    float xB0[4], xB1[4];
    #pragma unroll
    for (int rg = 0; rg < 4; ++rg) {
        int gj = Bj0 + quad * 4 + rg;
        xB0[rg] = x[gj * F + c0];
        xB1[rg] = x[gj * F + c1];
    }

    const int rq16 = 16 * ((l15 >> 2) & 3);        // h-swizzle offset for A-frag reads

    bar_lds();                                     // d_all visible to all waves

    // ---- fill: 4 threads per row write the 48-slot window as 6 packed b32 stores ----
    {
        int row = tid >> 2;                        // 0..63
        int lo4 = tid & 3;
        float d = d_all[row];
        int klo8 = klo_from_d(d) & ~7;             // octet-aligned window base
        if (lo4 == 0) klo8_lds[row] = (unsigned short)klo8;
        unsigned* e32 = (unsigned*)&e_lds[row * E_STRIDE];
        #pragma unroll
        for (int pass = 0; pass < 6; ++pass) {
            int loc = lo4 * 2 + pass * 8;          // even slot in 0..46
            float t0 = fmaf(-0.1f, (float)(klo8 + loc), d);
            float t1 = fmaf(-0.1f, (float)(klo8 + loc + 1), d);
            float e0 = exp2f(t0 * t0 * (-10.0f * L2E));
            float e1 = exp2f(t1 * t1 * (-10.0f * L2E));
            e32[loc >> 1] = cvt_pk_bf16(e0, e1);
        }
    }
    bar_lds();

    // ---- GEMM1: windowed E @ W1(regs); A-frags read per-lane at off = k - klo8[row],
    //      clamped to the zero pad when the octet misses the row's window ----
    floatx4 acc[4][2];
    {
        floatx4 bi0 = {b1L0, b1L0, b1L0, b1L0};
        floatx4 bi1 = {b1L1, b1L1, b1L1, b1L1};
        #pragma unroll
        for (int mt = 0; mt < 4; ++mt) { acc[mt][0] = bi0; acc[mt][1] = bi1; }
    }
    int klo8r[4];
    #pragma unroll
    for (int mt = 0; mt < 4; ++mt) klo8r[mt] = klo8_lds[mt*16 + l15];
    __builtin_amdgcn_s_setprio(1);
    #pragma unroll
    for (int ks = 0; ks < KE / 32; ++ks) {
        short8 af[4];
        #pragma unroll
        for (int mt = 0; mt < 4; ++mt) {
            int off = ks*32 + quad*8 - klo8r[mt];          // multiple of 8
            off = ((unsigned)off > 32u) ? 40 : off;        // 40.. = zero pad
            af[mt] = *(const short8*)&e_lds[(mt*16 + l15) * E_STRIDE + off];
        }
        #pragma unroll
        for (int mt = 0; mt < 4; ++mt) {
            acc[mt][0] = __builtin_amdgcn_mfma_f32_16x16x32_bf16(af[mt], w1f[ks][0], acc[mt][0], 0, 0, 0);
            acc[mt][1] = __builtin_amdgcn_mfma_f32_16x16x32_bf16(af[mt], w1f[ks][1], acc[mt][1], 0, 0, 0);
        }
    }
    __builtin_amdgcn_s_setprio(0);

    // ---- epilogue 1: h = ssp(acc) -> swizzled LDS (proven rq16 rotation) ----
    #pragma unroll
    for (int mt = 0; mt < 4; ++mt) {
        #pragma unroll
        for (int rg = 0; rg < 4; ++rg) {
            int row = mt*16 + quad*4 + rg;         // (row>>2)&3 == quad
            float h0 = ssp_l2(acc[mt][0][rg]);
            float h1 = ssp_l2(acc[mt][1][rg]);
            unsigned pk = cvt_pk_bf16(h0, h1);     // 1 VALU for both conversions
            h_lds[row * H_STRIDE + ((c0 + 16*quad) & 127)] = (unsigned short)pk;
            h_lds[row * H_STRIDE + ((c1 + 16*quad) & 127)] = (unsigned short)(pk >> 16);
        }
    }
    bar_lds();

    // ---- GEMM2: h[64 x 128] @ W2(regs, pre-scaled); acc2 init = bias*log2e ----
    floatx4 acc2[4][2];
    {
        floatx4 bi0 = {b2L0, b2L0, b2L0, b2L0};
        floatx4 bi1 = {b2L1, b2L1, b2L1, b2L1};
        #pragma unroll
        for (int mt = 0; mt < 4; ++mt) { acc2[mt][0] = bi0; acc2[mt][1] = bi1; }
    }
    __builtin_amdgcn_s_setprio(1);
    #pragma unroll
    for (int ks = 0; ks < F / 32; ++ks) {
        int ko = (ks*32 + quad*8 + rq16) & 127;
        short8 af[4];
        #pragma unroll
        for (int mt = 0; mt < 4; ++mt)
            af[mt] = *(const short8*)&h_lds[(mt*16 + l15) * H_STRIDE + ko];
        #pragma unroll
        for (int mt = 0; mt < 4; ++mt) {
            acc2[mt][0] = __builtin_amdgcn_mfma_f32_16x16x32_bf16(af[mt], w2f[ks][0], acc2[mt][0], 0, 0, 0);
            acc2[mt][1] = __builtin_amdgcn_mfma_f32_16x16x32_bf16(af[mt], w2f[ks][1], acc2[mt][1], 0, 0, 0);
        }
    }
    __builtin_amdgcn_s_setprio(0);

    // ---- epilogue 2: w = ssp(acc2); o_A += xB*w ; o_B += xA*w ----
    float oA0[4] = {0,0,0,0}, oA1[4] = {0,0,0,0};
    float oB0[4] = {0,0,0,0}, oB1[4] = {0,0,0,0};
    #pragma unroll
    for (int mt = 0; mt < 4; ++mt) {
        #pragma unroll
        for (int rg = 0; rg < 4; ++rg) {
            float w0 = ssp_l2(acc2[mt][0][rg]);
            float w1 = ssp_l2(acc2[mt][1][rg]);
            oA0[mt] = fmaf(xB0[rg], w0, oA0[mt]);
            oA1[mt] = fmaf(xB1[rg], w1, oA1[mt]);
            if (!diag) {
                oB0[rg] = fmaf(xA0[mt], w0, oB0[rg]);
                oB1[rg] = fmaf(xA1[mt], w1, oB1[rg]);
            }
        }
    }
    // reduce o_A across quads (rows complete within this slice) and scatter;
    // all atomics fire at the end — nothing waits on them
    #pragma unroll
    for (int mt = 0; mt < 4; ++mt) {
        oA0[mt] += __shfl_xor(oA0[mt], 16, 64); oA0[mt] += __shfl_xor(oA0[mt], 32, 64);
        oA1[mt] += __shfl_xor(oA1[mt], 16, 64); oA1[mt] += __shfl_xor(oA1[mt], 32, 64);
    }
    if (lane < 16) {
        #pragma unroll
        for (int mt = 0; mt < 4; ++mt) {
            int gi = Ai0 + s*4 + mt;
            atomicAdd(&out[gi * F + c0], oA0[mt]);
            atomicAdd(&out[gi * F + c1], oA1[mt]);
        }
    }
    // o_B partial over this slice's 4 ii-rows (one owner-thread per (jj,col))
    if (!diag) {
        #pragma unroll
        for (int rg = 0; rg < 4; ++rg) {
            int gj = Bj0 + quad * 4 + rg;
            atomicAdd(&out[gj * F + c0], oB0[rg]);
            atomicAdd(&out[gj * F + c1], oB1[rg]);
        }
    }
}

extern "C" void kernel_launch(void* const* d_in, const int* in_sizes, int n_in,
                              void* d_out, int out_size, void* d_ws, size_t ws_size,
                              hipStream_t stream) {
    const float* x  = (const float*)d_in[0];
    const float* r  = (const float*)d_in[1];
    const float* W1 = (const float*)d_in[2];
    const float* b1 = (const float*)d_in[3];
    const float* W2 = (const float*)d_in[4];
    const float* b2 = (const float*)d_in[5];
    float* out = (float*)d_out;

    unsigned short* W1s = (unsigned short*)d_ws;       // 24576 bf16 (pre-scaled by log2e)
    unsigned short* W2s = W1s + KE * F;                // 16384 bf16 (pre-scaled by log2e)

    prep_w<<<(NN * F) / 256, 256, 0, stream>>>(W1, W2, W1s, W2s, out);  // pack + zero out
    cfconv_main<<<NBLK, 256, 0, stream>>>(x, r, b1, b2, W1s, W2s, out);
}

// Round 8
// 117.694 us; speedup vs baseline: 1.0771x; 1.0140x over previous
//
#include <hip/hip_runtime.h>

#define F        128
#define NN       768
#define KE       192          // effective RBF range: d<=17.33 -> centers >=19.2 are dead
#define E_STRIDE 56           // elems; per-row 48-slot window (octet-aligned) + 8 slack
                              // 112 B/row = 7*16 -> b128-aligned rows, 7 coprime 8 spreads banks
#define H_STRIDE 136          // elems; 272 B stride == 16 mod 128 (proven conflict-free layout)
#define NT       48           // number of 16-row tiles
#define NPAIR    (NT*(NT+1)/2)   // 1176 upper-triangular tile pairs
#define NBLK     (NPAIR*4)       // 4704 blocks: one 64-pair slice each (s in blockIdx)

#define L2E 1.44269504f
#define LN2 0.69314718f

typedef __attribute__((ext_vector_type(8))) short short8;
typedef __attribute__((ext_vector_type(4))) float floatx4;

__device__ __forceinline__ unsigned short f2bf(float f) {
    union { float f; unsigned u; } v; v.f = f;
    return (unsigned short)((v.u + 0x8000u) >> 16);   // round-half-up (2 VALU)
}

// pack two f32 -> two bf16 (RTNE) in ONE VALU op
__device__ __forceinline__ unsigned cvt_pk_bf16(float lo, float hi) {
    unsigned r;
    asm("v_cvt_pk_bf16_f32 %0, %1, %2" : "=v"(r) : "v"(lo), "v"(hi));
    return r;
}

// z already in log2 domain (z = preact*log2e; bias*log2e folded into MFMA acc-init,
// log2e folded into packed W). ssp = ln2*(log2(1 + 2^z) - 1); bounded inputs.
__device__ __forceinline__ float ssp_l2(float zl2e) {
    float t = exp2f(zl2e);                  // v_exp_f32
    float u = __log2f(1.0f + t);            // v_add + v_log_f32
    return fmaf(LN2, u, -LN2);
}

// LDS-only barrier: drain DS ops, do NOT drain vmcnt -> out-atomics stay in flight
// (no cross-wave communication through global memory inside this kernel)
__device__ __forceinline__ void bar_lds() {
    asm volatile("s_waitcnt lgkmcnt(0)" ::: "memory");
    __builtin_amdgcn_s_barrier();
}

__device__ __forceinline__ int klo_from_d(float d) {
    int k = (int)ceilf(fmaf(10.0f, d, -13.0f));  // |d - 0.1k| > 1.3 -> e < 5e-8
    k &= ~1;
    return k < 0 ? 0 : (k > KE - 32 ? KE - 32 : k);
}

// Pack W1[0:192][128] and W2[128][128] (f32, PRE-SCALED by log2e) into bf16 MFMA
// B-fragment order, and zero the output buffer (replaces a separate memset node).
// COALESCED READ / permuted write (gather->scatter swap; writes are L2-absorbed):
// src elem (k,n) -> frag = (k>>5)*8 + (n>>4); dst = (frag*64 + ((k>>3)&3)*16 + (n&15))*8 + (k&7)
__global__ void prep_w(const float* __restrict__ W1, const float* __restrict__ W2,
                       unsigned short* __restrict__ W1s, unsigned short* __restrict__ W2s,
                       float* __restrict__ out) {
    int idx = blockIdx.x * 256 + threadIdx.x;          // grid 384*256 = 98304
    if (idx < (NN * F) / 4) {                          // vectorized zero of out (24576 float4)
        floatx4 z = {0.f, 0.f, 0.f, 0.f};
        ((floatx4*)out)[idx] = z;
    }
    if (idx < KE * F) {                                // 24576: linear read of W1
        int k = idx >> 7, n = idx & 127;
        int frag = (k >> 5) * 8 + (n >> 4);
        int dst = (frag * 64 + ((k >> 3) & 3) * 16 + (n & 15)) * 8 + (k & 7);
        W1s[dst] = f2bf(W1[idx] * L2E);
    } else if (idx < KE * F + F * F) {                 // next 16384: linear read of W2
        int j = idx - KE * F;
        int k = j >> 7, n = j & 127;
        int frag = (k >> 5) * 8 + (n >> 4);
        int dst = (frag * 64 + ((k >> 3) & 3) * 16 + (n & 15)) * 8 + (k & 7);
        W2s[dst] = f2bf(W2[j] * L2E);
    }
}

// One block = one 64-pair slice (4 A-rows x 16 B-cols) of one tile pair.
// W-fragments are NOT register-hoisted: loaded in-loop from L2 (80 KB, device-hot).
// Round-7 post-mortem: pinning 80 VGPRs of W forced the allocator to VGPR=84 with
// heavy remat/reload inside the GEMM loops (invisible in FETCH — L2 hits). In-loop
// loads give the allocator a sane problem at the same VMEM count.
// (256,2): allocator free, no spills. DO NOT tighten (rounds 2/3: spill storms).
__global__ __launch_bounds__(256, 2) void cfconv_main(
    const float* __restrict__ x, const float* __restrict__ r,
    const float* __restrict__ b1, const float* __restrict__ b2,
    const unsigned short* __restrict__ W1s, const unsigned short* __restrict__ W2s,
    float* __restrict__ out)
{
    // Windowed E-tile: row rr stores e(klo8[rr] + loc) for loc in [0,40); slots
    // 40..47 are stored as exact 0 (|d-0.1k| >= 2.1 there -> e < 1e-19) and serve
    // as the clamp-read zero pad for out-of-window octets.
    __shared__ __align__(16) unsigned short e_lds[64 * E_STRIDE];   // 7168 B
    __shared__ __align__(16) unsigned short h_lds[64 * H_STRIDE];   // 17408 B
    __shared__ float d_all[64];                                     // exact f32 d per pair
    __shared__ unsigned short klo8_lds[64];                         // per-row window base
    // total LDS = 24960 B

    const int tid  = threadIdx.x;
    const int lane = tid & 63;
    const int wave = tid >> 6;
    const int quad = lane >> 4;
    const int l15  = lane & 15;

    // ---- decode (tile pair, s-slice); f(A) = A*(97-A)/2 ----
    int bidx = blockIdx.x;
    const int s = bidx & 3;
    int b = bidx >> 2;                         // 0..1175 upper-triangular pair id
    int A = (int)((97.0f - sqrtf(9409.0f - 8.0f * (float)b)) * 0.5f);
    while ((A + 1) * (97 - (A + 1)) / 2 <= b) ++A;
    while (A * (97 - A) / 2 > b) --A;
    const int B = A + (b - A * (97 - A) / 2);
    const int Ai0 = A * 16, Bj0 = B * 16;
    const bool diag = (A == B);

    // ---- distances for this slice's 64 (ii,jj) pairs; rr = i_loc*16 + j_loc ----
    if (tid < 64) {
        int gi = Ai0 + s * 4 + (tid >> 4), gj = Bj0 + (tid & 15);
        float dx = r[gi*3+0] - r[gj*3+0];
        float dy = r[gi*3+1] - r[gj*3+1];
        float dz = r[gi*3+2] - r[gj*3+2];
        float sq = dx*dx + dy*dy + dz*dz;
        d_all[tid] = sq > 0.0f ? sqrtf(sq) : 0.0f;
    }

    const int c0 = wave * 32 + l15;                // this wave's column strip
    const int c1 = c0 + 16;
    const float b1L0 = b1[c0] * L2E, b1L1 = b1[c1] * L2E;   // bias pre-scaled to log2 domain
    const float b2L0 = b2[c0] * L2E, b2L1 = b2[c1] * L2E;

    // ---- xA/xB loads FIRST (oldest in the vmem queue); all out-atomics issue last ----
    float xA0[4], xA1[4];
    #pragma unroll
    for (int mt = 0; mt < 4; ++mt) {
        int gi = Ai0 + s*4 + mt;
        xA0[mt] = x[gi * F + c0];
        xA1[mt] = x[gi * F + c1];
    }
    // x rows of the B tile, indexed by this thread's quad: jj = quad*4 + rg
    float xB0[4], xB1[4];
    #pragma unroll
    for (int rg = 0; rg < 4; ++rg) {
        int gj = Bj0 + quad * 4 + rg;
        xB0[rg] = x[gj * F + c0];
        xB1[rg] = x[gj * F + c1];
    }

    const int rq16 = 16 * ((l15 >> 2) & 3);        // h-swizzle offset for A-frag reads
    // per-wave W fragment base (elements): frag index (ks*8 + wave*2 + j)
    const unsigned short* w1base = W1s + (wave * 2 * 64 + lane) * 8;
    const unsigned short* w2base = W2s + (wave * 2 * 64 + lane) * 8;

    bar_lds();                                     // d_all visible to all waves

    // ---- fill: 4 threads per row; 5 computed passes (slots 0..39) + zero pad 40..47 ----
    {
        int row = tid >> 2;                        // 0..63
        int lo4 = tid & 3;
        float d = d_all[row];
        int klo8 = klo_from_d(d) & ~7;             // octet-aligned window base
        if (lo4 == 0) klo8_lds[row] = (unsigned short)klo8;
        unsigned* e32 = (unsigned*)&e_lds[row * E_STRIDE];
        #pragma unroll
        for (int pass = 0; pass < 5; ++pass) {
            int loc = lo4 * 2 + pass * 8;          // even slot in 0..38
            float t0 = fmaf(-0.1f, (float)(klo8 + loc), d);
            float t1 = fmaf(-0.1f, (float)(klo8 + loc + 1), d);
            float e0 = exp2f(t0 * t0 * (-10.0f * L2E));
            float e1 = exp2f(t1 * t1 * (-10.0f * L2E));
            e32[loc >> 1] = cvt_pk_bf16(e0, e1);
        }
        e32[20 + lo4] = 0u;                        // slots 40..47: exact zero pad
    }
    bar_lds();

    // ---- GEMM1: windowed E @ W1(L2-streamed); A-frags read per-lane at
    //      off = k - klo8[row], clamped to the zero pad when outside the window ----
    floatx4 acc[4][2];
    {
        floatx4 bi0 = {b1L0, b1L0, b1L0, b1L0};
        floatx4 bi1 = {b1L1, b1L1, b1L1, b1L1};
        #pragma unroll
        for (int mt = 0; mt < 4; ++mt) { acc[mt][0] = bi0; acc[mt][1] = bi1; }
    }
    int klo8r[4];
    #pragma unroll
    for (int mt = 0; mt < 4; ++mt) klo8r[mt] = klo8_lds[mt*16 + l15];
    __builtin_amdgcn_s_setprio(1);
    #pragma unroll
    for (int ks = 0; ks < KE / 32; ++ks) {
        short8 w0 = *(const short8*)&w1base[(ks*8 + 0) * 512];   // 512 = 64 lanes * 8 elems
        short8 w1 = *(const short8*)&w1base[(ks*8 + 1) * 512];
        short8 af[4];
        #pragma unroll
        for (int mt = 0; mt < 4; ++mt) {
            int off = ks*32 + quad*8 - klo8r[mt];          // multiple of 8
            off = ((unsigned)off > 32u) ? 40 : off;        // 40.. = zero pad
            af[mt] = *(const short8*)&e_lds[(mt*16 + l15) * E_STRIDE + off];
        }
        #pragma unroll
        for (int mt = 0; mt < 4; ++mt) {
            acc[mt][0] = __builtin_amdgcn_mfma_f32_16x16x32_bf16(af[mt], w0, acc[mt][0], 0, 0, 0);
            acc[mt][1] = __builtin_amdgcn_mfma_f32_16x16x32_bf16(af[mt], w1, acc[mt][1], 0, 0, 0);
        }
    }
    __builtin_amdgcn_s_setprio(0);

    // ---- epilogue 1: h = ssp(acc) -> swizzled LDS (proven rq16 rotation) ----
    #pragma unroll
    for (int mt = 0; mt < 4; ++mt) {
        #pragma unroll
        for (int rg = 0; rg < 4; ++rg) {
            int row = mt*16 + quad*4 + rg;         // (row>>2)&3 == quad
            float h0 = ssp_l2(acc[mt][0][rg]);
            float h1 = ssp_l2(acc[mt][1][rg]);
            unsigned pk = cvt_pk_bf16(h0, h1);     // 1 VALU for both conversions
            h_lds[row * H_STRIDE + ((c0 + 16*quad) & 127)] = (unsigned short)pk;
            h_lds[row * H_STRIDE + ((c1 + 16*quad) & 127)] = (unsigned short)(pk >> 16);
        }
    }
    bar_lds();

    // ---- GEMM2: h[64 x 128] @ W2(L2-streamed); acc2 init = bias*log2e ----
    floatx4 acc2[4][2];
    {
        floatx4 bi0 = {b2L0, b2L0, b2L0, b2L0};
        floatx4 bi1 = {b2L1, b2L1, b2L1, b2L1};
        #pragma unroll
        for (int mt = 0; mt < 4; ++mt) { acc2[mt][0] = bi0; acc2[mt][1] = bi1; }
    }
    __builtin_amdgcn_s_setprio(1);
    #pragma unroll
    for (int ks = 0; ks < F / 32; ++ks) {
        short8 w0 = *(const short8*)&w2base[(ks*8 + 0) * 512];
        short8 w1 = *(const short8*)&w2base[(ks*8 + 1) * 512];
        int ko = (ks*32 + quad*8 + rq16) & 127;
        short8 af[4];
        #pragma unroll
        for (int mt = 0; mt < 4; ++mt)
            af[mt] = *(const short8*)&h_lds[(mt*16 + l15) * H_STRIDE + ko];
        #pragma unroll
        for (int mt = 0; mt < 4; ++mt) {
            acc2[mt][0] = __builtin_amdgcn_mfma_f32_16x16x32_bf16(af[mt], w0, acc2[mt][0], 0, 0, 0);
            acc2[mt][1] = __builtin_amdgcn_mfma_f32_16x16x32_bf16(af[mt], w1, acc2[mt][1], 0, 0, 0);
        }
    }
    __builtin_amdgcn_s_setprio(0);

    // ---- epilogue 2: w = ssp(acc2); o_A += xB*w ; o_B += xA*w ----
    float oA0[4] = {0,0,0,0}, oA1[4] = {0,0,0,0};
    float oB0[4] = {0,0,0,0}, oB1[4] = {0,0,0,0};
    #pragma unroll
    for (int mt = 0; mt < 4; ++mt) {
        #pragma unroll
        for (int rg = 0; rg < 4; ++rg) {
            float w0 = ssp_l2(acc2[mt][0][rg]);
            float w1 = ssp_l2(acc2[mt][1][rg]);
            oA0[mt] = fmaf(xB0[rg], w0, oA0[mt]);
            oA1[mt] = fmaf(xB1[rg], w1, oA1[mt]);
            if (!diag) {
                oB0[rg] = fmaf(xA0[mt], w0, oB0[rg]);
                oB1[rg] = fmaf(xA1[mt], w1, oB1[rg]);
            }
        }
    }
    // reduce o_A across quads (rows complete within this slice) and scatter;
    // all atomics fire at the end — nothing waits on them
    #pragma unroll
    for (int mt = 0; mt < 4; ++mt) {
        oA0[mt] += __shfl_xor(oA0[mt], 16, 64); oA0[mt] += __shfl_xor(oA0[mt], 32, 64);
        oA1[mt] += __shfl_xor(oA1[mt], 16, 64); oA1[mt] += __shfl_xor(oA1[mt], 32, 64);
    }
    if (lane < 16) {
        #pragma unroll
        for (int mt = 0; mt < 4; ++mt) {
            int gi = Ai0 + s*4 + mt;
            atomicAdd(&out[gi * F + c0], oA0[mt]);
            atomicAdd(&out[gi * F + c1], oA1[mt]);
        }
    }
    // o_B partial over this slice's 4 ii-rows (one owner-thread per (jj,col))
    if (!diag) {
        #pragma unroll
        for (int rg = 0; rg < 4; ++rg) {
            int gj = Bj0 + quad * 4 + rg;
            atomicAdd(&out[gj * F + c0], oB0[rg]);
            atomicAdd(&out[gj * F + c1], oB1[rg]);
        }
    }
}

extern "C" void kernel_launch(void* const* d_in, const int* in_sizes, int n_in,
                              void* d_out, int out_size, void* d_ws, size_t ws_size,
                              hipStream_t stream) {
    const float* x  = (const float*)d_in[0];
    const float* r  = (const float*)d_in[1];
    const float* W1 = (const float*)d_in[2];
    const float* b1 = (const float*)d_in[3];
    const float* W2 = (const float*)d_in[4];
    const float* b2 = (const float*)d_in[5];
    float* out = (float*)d_out;

    unsigned short* W1s = (unsigned short*)d_ws;       // 24576 bf16 (pre-scaled by log2e)
    unsigned short* W2s = W1s + KE * F;                // 16384 bf16 (pre-scaled by log2e)

    prep_w<<<(NN * F) / 256, 256, 0, stream>>>(W1, W2, W1s, W2s, out);  // pack + zero out
    cfconv_main<<<NBLK, 256, 0, stream>>>(x, r, b1, b2, W1s, W2s, out);
}